// Round 10
// baseline (275.431 us; speedup 1.0000x reference)
//
#include <hip/hip_runtime.h>
#include <math.h>

// SineSPE R10: 32x32x16 MFMA (8 ops/chunk/wave, -17% matrix-pipe), af-prefetch
// before synth, setprio(1) around MFMA cluster, coalesced trig table [h][t][g][l].
// Dataflow = R9: B in registers from frag-ordered bpack (L2-resident), A-only LDS
// (2x8K dbuf) + pos/cs, single barrier per chunk. Fallback: validated R6 path.

#define NH 8
#define NF 64
#define NK 10
#define NR 256
#define NB 4
#define NL 2048
#define KTOT 1280
#define BK 32
#define NCH (KTOT/BK)        // 40
#define NFRAG_B 16
#define WS_BPACK ((size_t)NB*NH*NCH*NFRAG_B*1024)          // 20,971,520
#define WS_TRIG  ((size_t)NH*NCH*4*2048*16)                // 41,943,040
#define WS_NEED2 (WS_BPACK + WS_TRIG)                      // 62,914,560

typedef __attribute__((ext_vector_type(8))) short short8;
typedef __attribute__((ext_vector_type(4))) float f32x4;
typedef __attribute__((ext_vector_type(16))) float f32x16;
typedef __attribute__((ext_vector_type(4))) unsigned int u32x4;
typedef __attribute__((ext_vector_type(2))) unsigned int u32x2;

static __device__ __forceinline__ unsigned short f2b(float f) {  // fp32->bf16 RNE
    unsigned x = __float_as_uint(f);
    return (unsigned short)((x + 0x7FFFu + ((x >> 16) & 1u)) >> 16);
}
static __device__ __forceinline__ unsigned int pk2(float a, float b) {
    return (unsigned int)f2b(a) | ((unsigned int)f2b(b) << 16);
}
static __device__ __forceinline__ unsigned int cvtpk(float lo, float hi) {
    unsigned int r;
    asm("v_cvt_pk_bf16_f32 %0, %1, %2" : "=v"(r) : "v"(lo), "v"(hi));
    return r;
}
static __device__ __forceinline__ void gload_lds16(const void* g, void* l) {
    __builtin_amdgcn_global_load_lds(
        (const __attribute__((address_space(1))) unsigned int*)g,
        (__attribute__((address_space(3))) unsigned int*)l, 16, 0, 0);
}

// -------- prep (32x32 frag order): z -> bf16 Bpack, gains folded -------------
// frag fid = ks*8 + coltile; lane l: col = coltile*32 + (l&31), k8 = ks*16+(l>>5)*8
__global__ __launch_bounds__(256)
void spe_prep32(const float* __restrict__ z, const float* __restrict__ gains,
                unsigned char* __restrict__ bpack)
{
    __shared__ float s_g[NF*NK];
    const int ch  = blockIdx.x;
    const int bh  = blockIdx.y;
    const int h   = bh & 7;
    const int tid = threadIdx.x;
    for (int i = tid; i < NF*NK; i += 256)
        s_g[i] = log1pf(expf(gains[h*NF*NK + i])) * 0.0078125f;  // softplus/128
    __syncthreads();
    const float* zb = z + (size_t)bh * KTOT * NR;
    unsigned char* dst = bpack + ((size_t)(bh*NCH + ch) * NFRAG_B) * 1024;
    #pragma unroll
    for (int it = 0; it < 4; ++it) {
        const int s   = tid + 256*it;        // slot 0..1023
        const int fid = s >> 6;              // 0..15
        const int l   = s & 63;
        const int ks  = fid >> 3;
        const int ct  = fid & 7;
        const int r   = ct*32 + (l & 31);
        const int k0  = ch*BK + ks*16 + (l >> 5)*8;
        u32x4 wv;
        #pragma unroll
        for (int jp = 0; jp < 4; ++jp) {
            const int ka = k0 + 2*jp, kb = ka + 1;
            const int fa = (ka*3277) >> 16; int sa = ka - fa*20; if (sa >= NK) sa -= NK;
            const int fb = (kb*3277) >> 16; int sb = kb - fb*20; if (sb >= NK) sb -= NK;
            const float va = zb[(size_t)ka*NR + r] * s_g[fa*NK + sa];
            const float vb = zb[(size_t)kb*NR + r] * s_g[fb*NK + sb];
            wv[jp] = pk2(va, vb);
        }
        *(u32x4*)(dst + (size_t)s*16) = wv;
    }
}

// -------- prep (16x16 frag order) for the fallback path ----------------------
__global__ __launch_bounds__(256)
void spe_prep16(const float* __restrict__ z, const float* __restrict__ gains,
                unsigned char* __restrict__ bpack)
{
    __shared__ float s_g[NF*NK];
    const int ch  = blockIdx.x;
    const int bh  = blockIdx.y;
    const int h   = bh & 7;
    const int tid = threadIdx.x;
    for (int i = tid; i < NF*NK; i += 256)
        s_g[i] = log1pf(expf(gains[h*NF*NK + i])) * 0.0078125f;
    __syncthreads();
    const float* zb = z + (size_t)bh * KTOT * NR;
    unsigned char* dst = bpack + ((size_t)(bh*NCH + ch) * NFRAG_B) * 1024;
    #pragma unroll
    for (int it = 0; it < 4; ++it) {
        const int s  = tid + 256*it;
        const int fi = s >> 6;
        const int l  = s & 63;
        const int r  = fi*16 + (l & 15);
        const int k0 = ch*BK + (l >> 4)*8;
        u32x4 wv;
        #pragma unroll
        for (int jp = 0; jp < 4; ++jp) {
            const int ka = k0 + 2*jp, kb = ka + 1;
            const int fa = (ka*3277) >> 16; int sa = ka - fa*20; if (sa >= NK) sa -= NK;
            const int fb = (kb*3277) >> 16; int sb = kb - fb*20; if (sb >= NK) sb -= NK;
            const float va = zb[(size_t)ka*NR + r] * s_g[fa*NK + sa];
            const float vb = zb[(size_t)kb*NR + r] * s_g[fb*NK + sb];
            wv[jp] = pk2(va, vb);
        }
        *(u32x4*)(dst + (size_t)s*16) = wv;
    }
}

// -------- trig table: [h][t][g(4)][l(2048)] u32x4 of (cos,sin)bf16 -----------
// g = kstep*2 + kgrp; entry(h,t,g,l) covers kidx = t*16 + g*4 + {0..3} at row l
__global__ __launch_bounds__(256)
void spe_trig(const float* __restrict__ freqs, unsigned int* __restrict__ trig)
{
    const int t = blockIdx.x;   // chunk 0..39
    const int h = blockIdx.y;
    const int tid = threadIdx.x;
    #pragma unroll
    for (int it = 0; it < 32; ++it) {
        const int site = tid + 256*it;     // 8192 = 4 g x 2048 l
        const int l = site & 2047;
        const int g = site >> 11;
        u32x4 wv;
        #pragma unroll
        for (int j = 0; j < 4; ++j) {
            const int kidx = t*16 + g*4 + j;             // = f*10+k
            const float fv = freqs[h*640 + kidx];
            const float fr = 0.5f / (1.0f + expf(-fv));  // rev/step
            const float x  = __builtin_amdgcn_fractf(fr * (float)l);
            wv[j] = pk2(__builtin_amdgcn_cosf(x), __builtin_amdgcn_sinf(x));
        }
        *(u32x4*)(trig + ((size_t)((h*NCH + t)*4 + g)*2048 + l)*4) = wv;
    }
}

// -------- main5: 32x32x16 MFMA, B-in-regs, A-only LDS, single barrier --------
#define OFF5_A   0              // 2 x 8192
#define OFF5_POS 16384          // [2 qk][64 f][64 rows] u16 = 16384
#define OFF5_CS  32768          // 640 float2 = 5120
#define SMEM5_SZ 37888

__global__ __launch_bounds__(512, 4)
void spe_main5(const float* __restrict__ queries, const float* __restrict__ keys,
               const float* __restrict__ offsets,
               const unsigned char* __restrict__ bpack,
               const unsigned int* __restrict__ trig,
               float* __restrict__ out)
{
    __shared__ __attribute__((aligned(16))) unsigned char smem[SMEM5_SZ];
    const int tid  = threadIdx.x;
    const int lane = tid & 63;
    const int w    = tid >> 6;

    // XCD-locality decode: fb&7 = h
    const int fb = blockIdx.x;            // 0..1023
    const int h  = fb & 7;
    const int b  = (fb >> 3) & 3;
    const int l0 = (fb >> 5) * 64;
    const int bh = b*NH + h;

    float2* ld_cs = (float2*)(smem + OFF5_CS);
    unsigned short* pos_t = (unsigned short*)(smem + OFF5_POS);

    for (int i = tid; i < NF*NK; i += 512) {
        const float xo = __builtin_amdgcn_fractf(offsets[h*640 + i] * 0.15915494309189535f);
        ld_cs[i] = make_float2(__builtin_amdgcn_cosf(xo), __builtin_amdgcn_sinf(xo));
    }
    {   // pos tiles -> bf16 transposed [qk][f][64 rows]
        const int r  = tid >> 2;            // 0..127: <64 q-row, >=64 k-row
        const int f0 = (tid & 3) * 16;
        const int rl = r & 63;
        const float* src = (r < 64)
            ? queries + ((size_t)((b*NL + l0 + rl)*NH + h))*NF + f0
            : keys    + ((size_t)((b*NL + l0 + rl)*NH + h))*NF + f0;
        unsigned short* pdst = pos_t + ((r >> 6) << 12);
        #pragma unroll
        for (int j = 0; j < 4; ++j) {
            const float4 v = *(const float4*)(src + j*4);
            const int f = f0 + j*4;
            pdst[(f+0)*64 + rl] = f2b(v.x);
            pdst[(f+1)*64 + rl] = f2b(v.y);
            pdst[(f+2)*64 + rl] = f2b(v.z);
            pdst[(f+3)*64 + rl] = f2b(v.w);
        }
    }

    const unsigned char* bp = bpack + (size_t)bh * ((size_t)NCH*NFRAG_B*1024);

    // MFMA roles: wq = q/k half, wn = 64-col quarter (2 coltiles of 32)
    const int wq = w >> 2, wn = w & 3;
    // synth roles: one A-frag slot per thread per chunk
    const int sqk  = w >> 2;
    const int ks_s = (w >> 1) & 1;
    const int rt_s = w & 1;
    const int row_s = rt_s*32 + (lane & 31);
    const int g_s   = ks_s*2 + (lane >> 5);        // 0..3 -> kidx group of 4
    const int a_w   = ((sqk*4 + ks_s*2 + rt_s) << 10) + (lane << 4);
    const unsigned int* tbase =
        trig + ((size_t)(h*NCH)*4 + g_s)*2048*4 + (size_t)(l0 + row_s)*4;
    const size_t tstep = (size_t)4*2048*4;         // u32 per chunk

    // prologue: trig(0), B(0)->regs, trig(1)
    u32x4 trEven = *(const u32x4*)(tbase);
    short8 bfEven[4], bfOdd[4];
    #pragma unroll
    for (int fi = 0; fi < 4; ++fi) {               // fi = ks*2 + ct
        const int fid = (fi >> 1)*8 + wn*2 + (fi & 1);
        bfEven[fi] = *(const short8*)(bp + (fid << 10) + lane*16);
    }
    u32x4 trOdd = *(const u32x4*)(tbase + tstep);
    __syncthreads();   // pos/cs visible

    f32x16 acc[2][2];
    #pragma unroll
    for (int mi = 0; mi < 2; ++mi)
        #pragma unroll
        for (int ni = 0; ni < 2; ++ni)
            #pragma unroll
            for (int q = 0; q < 16; ++q)
                acc[mi][ni][q] = 0.0f;

    // synth A(t): 4 kidx sites -> one b128 frag slot (8 bf16, k-ascending)
    auto synthA = [&](int t, const u32x4 tr) -> u32x4 {
        u32x4 av_;
        const int kb = t*16 + g_s*4;
        #pragma unroll
        for (int p = 0; p < 4; ++p) {
            const int kidx = kb + p;
            const int f    = (kidx * 6554) >> 16;          // /10
            const float ck = __uint_as_float(tr[p] << 16);
            const float sk = __uint_as_float(tr[p] & 0xffff0000u);
            const float pv = __uint_as_float(((unsigned)pos_t[sqk*4096 + f*64 + row_s]) << 16);
            float c, s;
            if (sqk == 0) {                                 // wave-uniform branch
                const float2 cs = ld_cs[kidx];              // broadcast read
                c = ck*cs.x - sk*cs.y;
                s = sk*cs.x + ck*cs.y;
            } else { c = ck; s = sk; }
            av_[p] = cvtpk(c*pv, s*pv);
        }
        return av_;
    };

    u32x4 av = synthA(0, trEven);

    auto iter = [&](int t, int par, short8 (&bfC)[4], short8 (&bfN)[4],
                    const u32x4 trUse, u32x4& trLoad) {
        *(u32x4*)(smem + OFF5_A + par*8192 + a_w) = av;
        asm volatile("s_waitcnt lgkmcnt(0)" ::: "memory");
        __builtin_amdgcn_sched_barrier(0);
        __builtin_amdgcn_s_barrier();              // A(t) visible; reads(t-1) done

        // af prefetch FIRST: ds latency hides under B-issue + synth VALU
        short8 af[2][2];
        #pragma unroll
        for (int ks = 0; ks < 2; ++ks)
            #pragma unroll
            for (int mi = 0; mi < 2; ++mi)
                af[ks][mi] = *(const short8*)(smem + OFF5_A + par*8192
                                              + ((wq*4 + ks*2 + mi) << 10) + (lane << 4));

        if (t + 1 < NCH) {                          // B(t+1) -> regs (L2)
            const unsigned char* bn = bp + (size_t)(t+1)*16384;
            #pragma unroll
            for (int fi = 0; fi < 4; ++fi) {
                const int fid = (fi >> 1)*8 + wn*2 + (fi & 1);
                bfN[fi] = *(const short8*)(bn + (fid << 10) + lane*16);
            }
        }
        if (t + 2 < NCH)
            trLoad = *(const u32x4*)(tbase + (size_t)(t+2)*tstep);

        if (t + 1 < NCH) av = synthA(t + 1, trUse); // VALU under MFMA shadow

        __builtin_amdgcn_s_setprio(1);
        #pragma unroll
        for (int ks = 0; ks < 2; ++ks)
            #pragma unroll
            for (int mi = 0; mi < 2; ++mi)
                #pragma unroll
                for (int ni = 0; ni < 2; ++ni)
                    acc[mi][ni] = __builtin_amdgcn_mfma_f32_32x32x16_bf16(
                        af[ks][mi], bfC[ks*2 + ni], acc[mi][ni], 0, 0, 0);
        __builtin_amdgcn_s_setprio(0);
    };

    #pragma unroll 1
    for (int t = 0; t < NCH; t += 2) {
        iter(t,     0, bfEven, bfOdd,  trOdd,  trEven);
        iter(t + 1, 1, bfOdd,  bfEven, trEven, trOdd);
    }

    // epilogue: 32x32 C/D layout col=lane&31, row=(reg&3)+8*(reg>>2)+4*(lane>>5)
    const size_t qk_off = (size_t)wq * ((size_t)NB*NL*NH*NR);
    const int col_b = wn*64 + (lane & 31);
    const int row_b = 4*(lane >> 5);
    #pragma unroll
    for (int mi = 0; mi < 2; ++mi) {
        #pragma unroll
        for (int ni = 0; ni < 2; ++ni) {
            const int rg = col_b + ni*32;
            #pragma unroll
            for (int q = 0; q < 16; ++q) {
                const int lg = l0 + mi*32 + row_b + (q & 3) + 8*(q >> 2);
                out[qk_off + ((size_t)((b*NL + lg)*NH + h))*NR + rg] = acc[mi][ni][q];
            }
        }
    }
}

// -------- fallback: validated R6 main (2-barrier, 16x16, B-DMA) --------------
#define OFF_B   0
#define OFF_A   49152
#define OFF_POS 57344
#define OFF_FR  73728
#define OFF_CO  76288
#define OFF_SO  78848
#define SMEM_SZ 81408

__global__ __launch_bounds__(512, 4)
void spe_main(const float* __restrict__ queries, const float* __restrict__ keys,
              const float* __restrict__ freqs, const float* __restrict__ offsets,
              const unsigned char* __restrict__ bpack, float* __restrict__ out)
{
    __shared__ __attribute__((aligned(16))) unsigned char smem[SMEM_SZ];
    const int tid  = threadIdx.x;
    const int lane = tid & 63;
    const int w    = tid >> 6;
    const int l0   = blockIdx.x * 64;
    const int bh   = blockIdx.y;
    const int b = bh >> 3, h = bh & 7;

    float* ld_fr = (float*)(smem + OFF_FR);
    float* ld_co = (float*)(smem + OFF_CO);
    float* ld_so = (float*)(smem + OFF_SO);
    unsigned short* pos_t = (unsigned short*)(smem + OFF_POS);

    for (int i = tid; i < NF*NK; i += 512) {
        const float fv = freqs[h*NF*NK + i];
        ld_fr[i] = 0.5f / (1.0f + expf(-fv));
        const float xo = __builtin_amdgcn_fractf(offsets[h*NF*NK + i] * 0.15915494309189535f);
        ld_co[i] = __builtin_amdgcn_cosf(xo);
        ld_so[i] = __builtin_amdgcn_sinf(xo);
    }
    {
        const int r  = tid >> 2;
        const int f0 = (tid & 3) * 16;
        const int rl = r & 63;
        const float* src = (r < 64)
            ? queries + ((size_t)((b*NL + l0 + rl)*NH + h))*NF + f0
            : keys    + ((size_t)((b*NL + l0 + rl)*NH + h))*NF + f0;
        unsigned short* pdst = pos_t + ((r >> 6) << 12);
        #pragma unroll
        for (int j = 0; j < 4; ++j) {
            const float4 v = *(const float4*)(src + j*4);
            const int f = f0 + j*4;
            pdst[(f+0)*64 + rl] = f2b(v.x);
            pdst[(f+1)*64 + rl] = f2b(v.y);
            pdst[(f+2)*64 + rl] = f2b(v.z);
            pdst[(f+3)*64 + rl] = f2b(v.w);
        }
    }
    __syncthreads();

    const unsigned char* bp = bpack + (size_t)bh * ((size_t)NCH*NFRAG_B*1024);
    const int fi0 = w*2;
    gload_lds16(bp + (size_t)fi0*1024 + lane*16,               smem + OFF_B + (fi0  <<10));
    gload_lds16(bp + (size_t)(fi0+1)*1024 + lane*16,           smem + OFF_B + ((fi0+1)<<10));
    gload_lds16(bp + (size_t)(NFRAG_B + fi0)*1024 + lane*16,   smem + OFF_B + 16384 + (fi0  <<10));
    gload_lds16(bp + (size_t)(NFRAG_B + fi0+1)*1024 + lane*16, smem + OFF_B + 16384 + ((fi0+1)<<10));

    const int wm = w >> 2, wn = w & 3;
    f32x4 acc[4][4];
    #pragma unroll
    for (int mi = 0; mi < 4; ++mi)
        #pragma unroll
        for (int ni = 0; ni < 4; ++ni)
            acc[mi][ni] = (f32x4){0.f, 0.f, 0.f, 0.f};

    const int rq   = ((w & 1) << 5) | (lane & 31);
    const int oct  = w >> 1;
    const int half = lane >> 5;
    const float lf = (float)(l0 + rq);
    const unsigned short* posq = pos_t;
    const unsigned short* posk = pos_t + 4096;
    const int aw_q = OFF_A + ((rq >> 4) << 10) + ((oct*16 + (rq & 15)) << 4) + (half << 3);
    const int aw_k = aw_q + 4096;

    auto synthA = [&](int t, u32x2& q01, u32x2& k01) {
        #pragma unroll
        for (int p = 0; p < 2; ++p) {
            const int kk   = t*BK + oct*8 + half*4 + p*2;
            const int f    = (kk*3277) >> 16;
            const int srem = kk - f*20;
            const int kidx = f*NK + (srem >> 1);
            const float x  = __builtin_amdgcn_fractf(ld_fr[kidx] * lf);
            const float ck = __builtin_amdgcn_cosf(x);
            const float sk = __builtin_amdgcn_sinf(x);
            const float co = ld_co[kidx], so = ld_so[kidx];
            const float cq = ck*co - sk*so;
            const float sq = sk*co + ck*so;
            const float pq = __uint_as_float(((unsigned)posq[f*64 + rq]) << 16);
            const float pk = __uint_as_float(((unsigned)posk[f*64 + rq]) << 16);
            q01[p] = cvtpk(cq*pq, sq*pq);
            k01[p] = cvtpk(ck*pk, sk*pk);
        }
    };

    u32x2 q01, k01;
    synthA(0, q01, k01);

    int bsel  = 0;
    int bsel2 = 2;
    for (int t = 0; t < NCH; ++t) {
        if (t < NCH-1) { asm volatile("s_waitcnt vmcnt(2)" ::: "memory"); }
        else           { asm volatile("s_waitcnt vmcnt(0)" ::: "memory"); }
        __builtin_amdgcn_sched_barrier(0);
        __builtin_amdgcn_s_barrier();

        if (t + 2 < NCH) {
            unsigned char* Bn = smem + OFF_B + bsel2*16384;
            gload_lds16(bp + (size_t)((t+2)*NFRAG_B + fi0)*1024 + lane*16,
                        Bn + (fi0<<10));
            gload_lds16(bp + (size_t)((t+2)*NFRAG_B + fi0+1)*1024 + lane*16,
                        Bn + ((fi0+1)<<10));
        }

        *(u32x2*)(smem + aw_q) = q01;
        *(u32x2*)(smem + aw_k) = k01;
        asm volatile("s_waitcnt lgkmcnt(0)" ::: "memory");
        __builtin_amdgcn_sched_barrier(0);
        __builtin_amdgcn_s_barrier();

        const unsigned char* Bc = smem + OFF_B + bsel*16384;
        short8 bf[4];
        #pragma unroll
        for (int ni = 0; ni < 4; ++ni)
            bf[ni] = *(const short8*)(Bc + ((wn*4 + ni) << 10) + (lane << 4));

        if (t + 1 < NCH) synthA(t + 1, q01, k01);

        #pragma unroll
        for (int mi = 0; mi < 4; ++mi) {
            const short8 af = *(const short8*)(smem + OFF_A + ((wm*4 + mi) << 10) + (lane << 4));
            #pragma unroll
            for (int ni = 0; ni < 4; ++ni)
                acc[mi][ni] = __builtin_amdgcn_mfma_f32_16x16x32_bf16(af, bf[ni], acc[mi][ni], 0, 0, 0);
        }

        bsel  = (bsel  == 2) ? 0 : bsel  + 1;
        bsel2 = (bsel2 == 2) ? 0 : bsel2 + 1;
    }

    const size_t qk_off = (size_t)wm * ((size_t)NB*NL*NH*NR);
    const int row_l = (lane >> 4) * 4;
    const int col_r = lane & 15;
    #pragma unroll
    for (int mi = 0; mi < 4; ++mi) {
        const int lg = l0 + mi*16 + row_l;
        #pragma unroll
        for (int ni = 0; ni < 4; ++ni) {
            const int rg = wn*64 + ni*16 + col_r;
            const f32x4 v = acc[mi][ni];
            #pragma unroll
            for (int q = 0; q < 4; ++q)
                out[qk_off + ((size_t)((b*NL + lg + q)*NH + h))*NR + rg] = v[q];
        }
    }
}

extern "C" void kernel_launch(void* const* d_in, const int* in_sizes, int n_in,
                              void* d_out, int out_size, void* d_ws, size_t ws_size,
                              hipStream_t stream) {
    const float* queries = (const float*)d_in[0];
    const float* keys    = (const float*)d_in[1];
    const float* z       = (const float*)d_in[2];
    const float* freqs   = (const float*)d_in[3];
    const float* offsets = (const float*)d_in[4];
    const float* gains   = (const float*)d_in[5];
    float* out = (float*)d_out;

    unsigned char* bpack = (unsigned char*)d_ws;

    if (ws_size >= WS_NEED2) {
        unsigned int* trig = (unsigned int*)(bpack + WS_BPACK);
        spe_prep32<<<dim3(NCH, NB*NH), 256, 0, stream>>>(z, gains, bpack);
        spe_trig<<<dim3(NCH, NH), 256, 0, stream>>>(freqs, trig);
        spe_main5<<<dim3(1024), 512, 0, stream>>>(queries, keys, offsets, bpack, trig, out);
    } else {
        spe_prep16<<<dim3(NCH, NB*NH), 256, 0, stream>>>(z, gains, bpack);
        spe_main<<<dim3(NL/64, NB*NH), 512, 0, stream>>>(queries, keys, freqs, offsets, bpack, out);
    }
}

// Round 13
// 125.089 us; speedup vs baseline: 2.2019x; 2.2019x over previous
//
#include <hip/hip_runtime.h>
#include <math.h>

// SineSPE R13 = R5 champion (q/k merged, 2-barrier chunk loop, offset-rotation,
// cvt_pk packing, XOR-swizzled A frags) + XCD-locality 1D block decode
// (h = bid&7 -> block's XCD L2 holds its 2.6MB bpack h-slice). Math byte-identical
// to the twice-validated R5 kernel. Fallback: validated R2-family kernel.

#define NH 8
#define NF 64
#define NK 10
#define NR 256
#define NB 4
#define NL 2048
#define KTOT 1280
#define BM 128               // fallback tile
#define BK 32
#define NCH (KTOT/BK)        // 40
#define NFRAG_B 16
#define WS_NEEDED ((size_t)NB*NH*NCH*NFRAG_B*1024)   // 20,971,520 B

typedef __attribute__((ext_vector_type(8))) short short8;
typedef __attribute__((ext_vector_type(4))) float f32x4;
typedef __attribute__((ext_vector_type(4))) unsigned int u32x4;
typedef __attribute__((ext_vector_type(2))) unsigned int u32x2;

static __device__ __forceinline__ unsigned short f2b(float f) {  // fp32->bf16 RNE
    unsigned x = __float_as_uint(f);
    return (unsigned short)((x + 0x7FFFu + ((x >> 16) & 1u)) >> 16);
}
static __device__ __forceinline__ unsigned int pk2(float a, float b) {
    return (unsigned int)f2b(a) | ((unsigned int)f2b(b) << 16);
}
static __device__ __forceinline__ unsigned int cvtpk(float lo, float hi) {
    unsigned int r;
    asm("v_cvt_pk_bf16_f32 %0, %1, %2" : "=v"(r) : "v"(lo), "v"(hi));
    return r;
}
static __device__ __forceinline__ void gload_lds16(const void* g, void* l) {
    __builtin_amdgcn_global_load_lds(
        (const __attribute__((address_space(1))) unsigned int*)g,
        (__attribute__((address_space(3))) unsigned int*)l, 16, 0, 0);
}

// ---------------- prep: z -> bf16 frag-ordered Bpack (gains folded) ----------
__global__ __launch_bounds__(256)
void spe_prep(const float* __restrict__ z, const float* __restrict__ gains,
              unsigned char* __restrict__ bpack)
{
    __shared__ float s_g[NF*NK];
    const int ch  = blockIdx.x;
    const int bh  = blockIdx.y;
    const int h   = bh & 7;
    const int tid = threadIdx.x;
    for (int i = tid; i < NF*NK; i += 256)
        s_g[i] = log1pf(expf(gains[h*NF*NK + i])) * 0.0078125f;  // softplus/128
    __syncthreads();
    const float* zb = z + (size_t)bh * KTOT * NR;
    unsigned char* dst = bpack + ((size_t)(bh*NCH + ch) * NFRAG_B) * 1024;
    #pragma unroll
    for (int it = 0; it < 4; ++it) {
        const int s  = tid + 256*it;
        const int fi = s >> 6;
        const int l  = s & 63;
        const int r  = fi*16 + (l & 15);
        const int k0 = ch*BK + (l >> 4)*8;
        u32x4 wv;
        #pragma unroll
        for (int jp = 0; jp < 4; ++jp) {
            const int ka = k0 + 2*jp, kb = ka + 1;
            const int fa = (ka*3277) >> 16; int sa = ka - fa*20; if (sa >= NK) sa -= NK;
            const int fb = (kb*3277) >> 16; int sb = kb - fb*20; if (sb >= NK) sb -= NK;
            const float va = zb[(size_t)ka*NR + r] * s_g[fa*NK + sa];
            const float vb = zb[(size_t)kb*NR + r] * s_g[fb*NK + sb];
            wv[jp] = pk2(va, vb);
        }
        *(u32x4*)(dst + (size_t)s*16) = wv;
    }
}

// ---------------- main (R5 champion, XCD decode) ----------------
#define OFF_B0  0
#define OFF_B1  16384
#define OFF_A   32768          // 8 KiB: frags 0-3 q-rows, 4-7 k-rows (XOR-swizzled)
#define OFF_POS 40960          // [2 qk][64 f][64 rows] bf16 = 16384 B
#define OFF_FR  57344          // 640 f32
#define OFF_CO  59904          // 640 f32
#define OFF_SO  62464          // 640 f32
#define SMEM_SZ 65024          // 63.5 KiB -> 2 blocks/CU

__global__ __launch_bounds__(512, 4)
void spe_main(const float* __restrict__ queries, const float* __restrict__ keys,
              const float* __restrict__ freqs, const float* __restrict__ offsets,
              const unsigned char* __restrict__ bpack, float* __restrict__ out)
{
    __shared__ __attribute__((aligned(16))) unsigned char smem[SMEM_SZ];
    const int tid  = threadIdx.x;
    const int lane = tid & 63;
    const int w    = tid >> 6;

    // XCD-locality decode: bid&7 = h -> each XCD's L2 holds one 2.6MB bpack slice
    const int fb = blockIdx.x;              // 0..1023
    const int h  = fb & 7;
    const int b  = (fb >> 3) & 3;
    const int l0 = (fb >> 5) * 64;          // 64 l-rows per block (q AND k)
    const int bh = b*NH + h;

    float* ld_fr = (float*)(smem + OFF_FR);
    float* ld_co = (float*)(smem + OFF_CO);
    float* ld_so = (float*)(smem + OFF_SO);
    unsigned short* pos_t = (unsigned short*)(smem + OFF_POS);

    for (int i = tid; i < NF*NK; i += 512) {
        const float fv = freqs[h*NF*NK + i];
        ld_fr[i] = 0.5f / (1.0f + expf(-fv));                                // rev/step
        const float xo = __builtin_amdgcn_fractf(offsets[h*NF*NK + i] * 0.15915494309189535f);
        ld_co[i] = __builtin_amdgcn_cosf(xo);
        ld_so[i] = __builtin_amdgcn_sinf(xo);
    }
    {   // pos tiles -> bf16 transposed [qk][f][64]
        const int r  = tid >> 2;            // 0..127: <64 q-row, >=64 k-row
        const int f0 = (tid & 3) * 16;
        const int rl = r & 63;
        const float* src = (r < 64)
            ? queries + ((size_t)((b*NL + l0 + rl)*NH + h))*NF + f0
            : keys    + ((size_t)((b*NL + l0 + rl)*NH + h))*NF + f0;
        unsigned short* pdst = pos_t + ((r >> 6) << 12);
        #pragma unroll
        for (int j = 0; j < 4; ++j) {
            const float4 v = *(const float4*)(src + j*4);
            const int f = f0 + j*4;
            pdst[(f+0)*64 + rl] = f2b(v.x);
            pdst[(f+1)*64 + rl] = f2b(v.y);
            pdst[(f+2)*64 + rl] = f2b(v.z);
            pdst[(f+3)*64 + rl] = f2b(v.w);
        }
    }
    __syncthreads();

    const unsigned char* bp = bpack + (size_t)bh * ((size_t)NCH*NFRAG_B*1024);
    const int fi0 = w*2;
    gload_lds16(bp + (size_t)fi0*1024 + lane*16,       smem + OFF_B0 + (fi0  <<10));
    gload_lds16(bp + (size_t)(fi0+1)*1024 + lane*16,   smem + OFF_B0 + ((fi0+1)<<10));

    const int wm = w >> 2, wn = w & 3;      // wm=0 -> q-half, wm=1 -> k-half
    f32x4 acc[4][4];
    #pragma unroll
    for (int mi = 0; mi < 4; ++mi)
        #pragma unroll
        for (int ni = 0; ni < 4; ++ni)
            acc[mi][ni] = (f32x4){0.f, 0.f, 0.f, 0.f};

    // A-synth map: rq = tid&63, oct = (tid>>6)&3, half = tid>>8 (2 pair-sites)
    const int rq   = tid & 63;
    const int oct  = (tid >> 6) & 3;
    const int half = tid >> 8;
    const float lf = (float)(l0 + rq);
    const unsigned short* posq = pos_t;
    const unsigned short* posk = pos_t + 4096;
    // logical A offsets (q-frag rq>>4, k-frag 4+(rq>>4)); swizzle: ^ (frag&3)<<5
    const int a_log_q = ((rq >> 4) << 10) + ((oct*16 + (rq & 15)) << 4) + (half << 3);
    const int aw_q = a_log_q ^ (((rq >> 4) & 3) << 5);
    const int aw_k = (a_log_q + 4096) ^ (((rq >> 4) & 3) << 5);

    auto synthA = [&](int t, u32x2& q01, u32x2& k01) {
        #pragma unroll
        for (int p = 0; p < 2; ++p) {
            const int kk   = t*BK + oct*8 + (half*2 + p)*2;   // even k
            const int f    = (kk*3277) >> 16;                 // kk/20
            const int srem = kk - f*20;
            const int kidx = f*NK + (srem >> 1);
            const float x  = __builtin_amdgcn_fractf(ld_fr[kidx] * lf);
            const float ck = __builtin_amdgcn_cosf(x);
            const float sk = __builtin_amdgcn_sinf(x);
            const float co = ld_co[kidx], so = ld_so[kidx];
            const float cq = ck*co - sk*so;                   // rotate by offset
            const float sq = sk*co + ck*so;
            const float pq = __uint_as_float(((unsigned)posq[f*64 + rq]) << 16);
            const float pk = __uint_as_float(((unsigned)posk[f*64 + rq]) << 16);
            q01[p] = cvtpk(cq*pq, sq*pq);
            k01[p] = cvtpk(ck*pk, sk*pk);
        }
    };

    u32x2 q01, k01;
    synthA(0, q01, k01);   // overlaps chunk-0 DMA flight

    for (int t = 0; t < NCH; ++t) {
        unsigned char* Bcur = smem + ((t & 1) ? OFF_B1 : OFF_B0);
        unsigned char* Bnxt = smem + ((t & 1) ? OFF_B0 : OFF_B1);

        asm volatile("s_waitcnt vmcnt(0)" ::: "memory");
        __builtin_amdgcn_sched_barrier(0);
        __builtin_amdgcn_s_barrier();                      // B(t) visible; prev readers done

        if (t + 1 < NCH) {
            gload_lds16(bp + (size_t)((t+1)*NFRAG_B + fi0)*1024 + lane*16,
                        Bnxt + (fi0<<10));
            gload_lds16(bp + (size_t)((t+1)*NFRAG_B + fi0+1)*1024 + lane*16,
                        Bnxt + ((fi0+1)<<10));
        }

        *(u32x2*)(smem + OFF_A + aw_q) = q01;              // A(t) -> LDS (swizzled)
        *(u32x2*)(smem + OFF_A + aw_k) = k01;
        asm volatile("s_waitcnt lgkmcnt(0)" ::: "memory");
        __builtin_amdgcn_sched_barrier(0);
        __builtin_amdgcn_s_barrier();                      // A(t) visible

        short8 bf[4];
        #pragma unroll
        for (int ni = 0; ni < 4; ++ni)
            bf[ni] = *(const short8*)(Bcur + ((wn*4 + ni) << 10) + (lane << 4));

        if (t + 1 < NCH) synthA(t + 1, q01, k01);          // VALU under MFMA shadow

        #pragma unroll
        for (int mi = 0; mi < 4; ++mi) {
            const int g    = wm*4 + mi;
            const int aoff = (g << 10) + (lane << 4);
            const short8 af = *(const short8*)(smem + OFF_A + (aoff ^ ((g & 3) << 5)));
            #pragma unroll
            for (int ni = 0; ni < 4; ++ni)
                acc[mi][ni] = __builtin_amdgcn_mfma_f32_16x16x32_bf16(af, bf[ni], acc[mi][ni], 0, 0, 0);
        }
    }

    // epilogue: wm selects q/k output; C/D layout col=lane&15, row=(lane>>4)*4+reg
    const size_t qk_off = (size_t)wm * ((size_t)NB*NL*NH*NR);
    const int row_l = (lane >> 4) * 4;
    const int col_r = lane & 15;
    #pragma unroll
    for (int mi = 0; mi < 4; ++mi) {
        const int lg = l0 + mi*16 + row_l;
        #pragma unroll
        for (int ni = 0; ni < 4; ++ni) {
            const int rg = wn*64 + ni*16 + col_r;
            const f32x4 v = acc[mi][ni];
            #pragma unroll
            for (int q = 0; q < 4; ++q)
                out[qk_off + ((size_t)((b*NL + lg + q)*NH + h))*NR + rg] = v[q];
        }
    }
}

// ---------------- fallback (validated R2 kernel) ----------------
#define FOFF_B   0
#define FOFF_A   32768
#define FOFF_POS 49152
#define FOFF_FR  65536
#define FOFF_OFS 68096
#define FOFF_GS  70656
#define FSMEM_SZ 73216

__global__ __launch_bounds__(512, 4)
void spe_mfma_fb(const float* __restrict__ queries, const float* __restrict__ keys,
                 const float* __restrict__ z, const float* __restrict__ freqs,
                 const float* __restrict__ offsets, const float* __restrict__ gains,
                 float* __restrict__ out)
{
    __shared__ __attribute__((aligned(16))) unsigned char smem[FSMEM_SZ];
    const int tid = threadIdx.x, lane = tid & 63;
    const int l0 = blockIdx.x * BM, bh = blockIdx.y;
    const int b = bh >> 3, h = bh & 7, isK = blockIdx.z;
    float* ld_fr = (float*)(smem + FOFF_FR);
    float* ld_of = (float*)(smem + FOFF_OFS);
    float* ld_gs = (float*)(smem + FOFF_GS);
    unsigned short* pos_t = (unsigned short*)(smem + FOFF_POS);
    for (int i = tid; i < NF*NK; i += 512) {
        const float fv = freqs[h*NF*NK + i];
        ld_fr[i] = 0.5f / (1.0f + expf(-fv));
        ld_of[i] = isK ? 0.0f : offsets[h*NF*NK + i] * 0.15915494309189535f;
        ld_gs[i] = log1pf(expf(gains[h*NF*NK + i])) * 0.0078125f;
    }
    {
        const float* pos = isK ? keys : queries;
        #pragma unroll
        for (int i = 0; i < 4; ++i) {
            const int lrow = (tid >> 4) + 32*i;
            const int f0 = (tid & 15) * 4;
            const float4 v = *(const float4*)(pos + ((size_t)((b*NL + l0 + lrow)*NH + h))*NF + f0);
            pos_t[(f0+0)*BM + lrow] = f2b(v.x); pos_t[(f0+1)*BM + lrow] = f2b(v.y);
            pos_t[(f0+2)*BM + lrow] = f2b(v.z); pos_t[(f0+3)*BM + lrow] = f2b(v.w);
        }
    }
    __syncthreads();
    const int w = tid >> 6, wm = w >> 2, wn = w & 3;
    f32x4 acc[4][4];
    #pragma unroll
    for (int mi = 0; mi < 4; ++mi)
        #pragma unroll
        for (int ni = 0; ni < 4; ++ni) acc[mi][ni] = (f32x4){0.f,0.f,0.f,0.f};
    const float* zbh = z + (size_t)(b*NH + h) * ((size_t)KTOT*NR);
    for (int ch = 0; ch < KTOT/64; ++ch) {
        const int fs0 = ch * 64;
        #pragma unroll
        for (int i = 0; i < 4; ++i) {
            const int tau = tid + 512*i, r = tau & 255, krun = tau >> 8;
            const float* zp = zbh + (size_t)(fs0 + krun*8)*NR + r;
            u32x4 wv2;
            #pragma unroll
            for (int jp = 0; jp < 4; ++jp) {
                const int fs = fs0 + krun*8 + 2*jp;
                const int f = (fs*3277) >> 16; const int rem = fs - f*20;
                const int km = (rem >= NK) ? rem - NK : rem;
                const int kn = ((rem+1) >= NK && (rem+1) < 2*NK) ? rem+1-NK : rem+1;
                const float sc0 = ld_gs[f*NK + km], sc1 = ld_gs[f*NK + (kn < NK ? kn : kn-NK)];
                wv2[jp] = pk2(zp[(2*jp)*NR]*sc0, zp[(2*jp+1)*NR]*sc1);
            }
            *(u32x4*)(smem + FOFF_B + ((((krun>>2)*16) + (r>>4)) << 10)
                                    + ((((krun&3)*16) + (r&15)) << 4)) = wv2;
        }
        #pragma unroll
        for (int i = 0; i < 2; ++i) {
            const int tau = tid + 512*i, m = tau & 127, krun = tau >> 7;
            const float lff = (float)(l0 + m);
            u32x4 wv2;
            #pragma unroll
            for (int jp = 0; jp < 4; ++jp) {
                const int fs = fs0 + krun*8 + 2*jp;
                const int f = (fs*3277) >> 16; const int rem = fs - f*20;
                const int kidx = f*NK + (rem >> 1);
                const float x = __builtin_amdgcn_fractf(ld_of[kidx] + ld_fr[kidx]*lff);
                const float c = __builtin_amdgcn_cosf(x), sn = __builtin_amdgcn_sinf(x);
                const float p = __uint_as_float(((unsigned)pos_t[f*BM + m]) << 16);
                wv2[jp] = pk2(c*p, sn*p);
            }
            *(u32x4*)(smem + FOFF_A + ((((krun>>2)*8) + (m>>4)) << 10)
                                    + ((((krun&3)*16) + (m&15)) << 4)) = wv2;
        }
        __syncthreads();
        #pragma unroll
        for (int ks = 0; ks < 2; ++ks) {
            short8 bf[4];
            #pragma unroll
            for (int ni = 0; ni < 4; ++ni)
                bf[ni] = *(const short8*)(smem + FOFF_B + ((ks*16 + wn*4 + ni) << 10) + (lane << 4));
            #pragma unroll
            for (int mi = 0; mi < 4; ++mi) {
                const short8 af = *(const short8*)(smem + FOFF_A + ((ks*8 + wm*4 + mi) << 10) + (lane << 4));
                #pragma unroll
                for (int ni = 0; ni < 4; ++ni)
                    acc[mi][ni] = __builtin_amdgcn_mfma_f32_16x16x32_bf16(af, bf[ni], acc[mi][ni], 0, 0, 0);
            }
        }
        __syncthreads();
    }
    const size_t qk_off = (size_t)isK * ((size_t)NB*NL*NH*NR);
    const int row_l = (lane >> 4) * 4, col_r = lane & 15;
    #pragma unroll
    for (int mi = 0; mi < 4; ++mi) {
        const int lg = l0 + wm*64 + mi*16 + row_l;
        #pragma unroll
        for (int ni = 0; ni < 4; ++ni) {
            const int rg = wn*64 + ni*16 + col_r;
            const f32x4 v = acc[mi][ni];
            #pragma unroll
            for (int q = 0; q < 4; ++q)
                out[qk_off + ((size_t)((b*NL + lg + q)*NH + h))*NR + rg] = v[q];
        }
    }
}

extern "C" void kernel_launch(void* const* d_in, const int* in_sizes, int n_in,
                              void* d_out, int out_size, void* d_ws, size_t ws_size,
                              hipStream_t stream) {
    const float* queries = (const float*)d_in[0];
    const float* keys    = (const float*)d_in[1];
    const float* z       = (const float*)d_in[2];
    const float* freqs   = (const float*)d_in[3];
    const float* offsets = (const float*)d_in[4];
    const float* gains   = (const float*)d_in[5];
    float* out = (float*)d_out;

    if (ws_size >= WS_NEEDED) {
        unsigned char* bpack = (unsigned char*)d_ws;
        spe_prep<<<dim3(NCH, NB*NH), 256, 0, stream>>>(z, gains, bpack);
        spe_main<<<dim3(1024), 512, 0, stream>>>(queries, keys, freqs, offsets, bpack, out);
    } else {
        spe_mfma_fb<<<dim3(NL/BM, NB*NH, 2), 512, 0, stream>>>(queries, keys, z, freqs, offsets, gains, out);
    }
}